// Round 1
// baseline (948.785 us; speedup 1.0000x reference)
//
#include <hip/hip_runtime.h>
#include <hip/hip_bf16.h>
#include <math.h>

// B=2048, C=128, H=4, L=2, P=106, D=32, N_PRED=217088
// Structure exploited:
//  - pred nodes receive exactly 1 edge -> alpha==1 -> agg_p[b*P+p] = v0[b]
//  - kqv_p GEMM collapses: scores via u[b,h]=Wk1_h@qn[b,h]; agg via y=sum(alpha*xp_row)
//  - xp never materialized: xp rows recomputed on the fly from U/V low-rank decomposition
//  - att output is a constant fill

__device__ __forceinline__ float wsum(float v){
#pragma unroll
  for (int o=32;o;o>>=1) v += __shfl_xor(v,o);
  return v;
}
__device__ __forceinline__ float gelu_f(float x){
  return 0.5f*x*(1.f+erff(x*0.70710678118654752f));
}
__device__ __forceinline__ float elu_f(float x){ return x>0.f?x:expm1f(x); }

template<int K, int N, bool GELU_IN>
__global__ __launch_bounds__(256) void gemm_bias(const float* __restrict__ X, int ldx,
    const float* __restrict__ W, const float* __restrict__ bias,
    float* __restrict__ Y, int rows)
{
  constexpr int RPB = 8;
  __shared__ float xs[RPB][K];
  const int r0 = blockIdx.x * RPB;
  const int tid = threadIdx.x;
  constexpr int V4 = RPB*(K/4);
  for (int i = tid; i < V4; i += 256){
    int r = i/(K/4); int kk = (i%(K/4))*4;
    float4 v = make_float4(0.f,0.f,0.f,0.f);
    if (r0+r < rows) v = *reinterpret_cast<const float4*>(X + (long)(r0+r)*ldx + kk);
    if (GELU_IN){ v.x=gelu_f(v.x); v.y=gelu_f(v.y); v.z=gelu_f(v.z); v.w=gelu_f(v.w); }
    *reinterpret_cast<float4*>(&xs[r][kk]) = v;
  }
  __syncthreads();
  constexpr int GROUPS = 256/N;   // N in {128,256}
  constexpr int RT = RPB/GROUPS;
  const int j = tid % N;
  const int rg = tid / N;
  float acc[RT];
#pragma unroll
  for (int r=0;r<RT;r++) acc[r] = bias ? bias[j] : 0.f;
#pragma unroll 4
  for (int k=0;k<K;k++){
    float w = W[k*N + j];
#pragma unroll
    for (int r=0;r<RT;r++) acc[r] += xs[rg*RT+r][k]*w;
  }
#pragma unroll
  for (int r=0;r<RT;r++){
    int rr = r0 + rg*RT + r;
    if (rr < rows) Y[(long)rr*N + j] = acc[r];
  }
}

// MODE 0: out = elu(LN(A;g,b))
// MODE 1: out = LN(A;g,b) + R
// MODE 2: out = elu(LN(sn*A + (1-sn)*Bx + R; g,b)), sn = sigmoid(skip[0])
template<int MODE>
__global__ __launch_bounds__(256) void ln_kernel(const float* __restrict__ A,
    const float* __restrict__ Bx, const float* __restrict__ R,
    const float* __restrict__ g, const float* __restrict__ beta,
    const float* __restrict__ skip, float* __restrict__ out, int rows)
{
  int row = blockIdx.x*4 + (threadIdx.x>>6);
  if (row >= rows) return;
  int lane = threadIdx.x & 63;
  int c0=lane, c1=lane+64;
  float t0, t1;
  if (MODE==2){
    float sn = 1.f/(1.f+expf(-skip[0])); float osn = 1.f - sn;
    t0 = sn*A[(long)row*128+c0] + osn*Bx[(long)row*128+c0] + R[(long)row*128+c0];
    t1 = sn*A[(long)row*128+c1] + osn*Bx[(long)row*128+c1] + R[(long)row*128+c1];
  } else {
    t0 = A[(long)row*128+c0]; t1 = A[(long)row*128+c1];
  }
  float m = wsum(t0+t1)*(1.f/128.f);
  float d0=t0-m, d1=t1-m;
  float var = wsum(d0*d0+d1*d1)*(1.f/128.f);
  float inv = rsqrtf(var+1e-5f);
  float y0 = d0*inv*g[c0]+beta[c0];
  float y1 = d1*inv*g[c1]+beta[c1];
  if (MODE==0 || MODE==2){ y0=elu_f(y0); y1=elu_f(y1); }
  if (MODE==1){ y0 += R[(long)row*128+c0]; y1 += R[(long)row*128+c1]; }
  out[(long)row*128+c0]=y0; out[(long)row*128+c1]=y1;
}

// in-place center rows, write ||centered||^2
__global__ __launch_bounds__(256) void center_stats(float* __restrict__ M,
    float* __restrict__ snorm, int rows)
{
  int row = blockIdx.x*4 + (threadIdx.x>>6);
  if (row >= rows) return;
  int lane = threadIdx.x & 63;
  float t0=M[(long)row*128+lane], t1=M[(long)row*128+lane+64];
  float m = wsum(t0+t1)*(1.f/128.f);
  t0-=m; t1-=m;
  float ss = wsum(t0*t0+t1*t1);
  M[(long)row*128+lane]=t0; M[(long)row*128+lane+64]=t1;
  if (lane==0) snorm[row]=ss;
}

// Wout[c][outoff+h*32+e] = sum_d Win[c*384+inoff+h*32+d]*rel[h*1024+d*32+e]; same for bias
__global__ __launch_bounds__(256) void fold_rel(const float* __restrict__ Win,
    const float* __restrict__ bin, int inoff,
    const float* __restrict__ rel,
    float* __restrict__ Wout, float* __restrict__ bout, int outoff)
{
  int h = blockIdx.x;
  __shared__ float rl[1024];
  for (int i=threadIdx.x;i<1024;i+=256) rl[i]=rel[h*1024+i];
  __syncthreads();
  int e = threadIdx.x & 31;
  int cg = threadIdx.x >> 5;
  for (int c=cg;c<128;c+=8){
    float acc=0.f;
#pragma unroll
    for (int d=0;d<32;d++) acc += Win[c*384 + inoff + h*32 + d]*rl[d*32+e];
    Wout[c*256 + outoff + h*32 + e]=acc;
  }
  if (threadIdx.x<32){
    float acc=0.f;
#pragma unroll
    for (int d=0;d<32;d++) acc += bin[inoff + h*32 + d]*rl[d*32+e];
    bout[outoff + h*32 + e]=acc;
  }
}

__global__ void copy_q(const float* __restrict__ kqvw, const float* __restrict__ kqvb,
                       float* __restrict__ Wout, float* __restrict__ bout)
{
  int idx = blockIdx.x*256 + threadIdx.x;
  if (idx < 16384){ int c = idx>>7, j = idx&127; Wout[c*256 + j] = kqvw[c*384 + 128 + j]; }
  if (idx < 128) bout[idx] = kqvb[128 + idx];
}

template<int LAYER>
__global__ __launch_bounds__(256) void attn_kernel(
    const float* __restrict__ A1, const float* __restrict__ Up,
    const float* __restrict__ sa1,
    const float* __restrict__ B1v, const float* __restrict__ Vn,
    const float* __restrict__ sb1,
    const float* __restrict__ qn,        // 2048x256, cols 0..127 = q
    const float* __restrict__ Wpred, const float* __restrict__ bpred,
    const float* __restrict__ p_rel_l1,
    const float* __restrict__ lin_pg, const float* __restrict__ lin_pbeta,
    const float* __restrict__ W0row,
    const float* __restrict__ ln_pg0, const float* __restrict__ ln_pbeta0,
    const float* __restrict__ skip_p,
    float* __restrict__ agg_out)
{
  __shared__ float tile[106][128];
  __shared__ float Bv[128], Vv[128], qs[128], W0s[128], gA[128], bA[128], g0[128], b0[128];
  __shared__ float us[4][128];
  __shared__ float ss[4][128];
  __shared__ float ys[4][128];
  __shared__ float c0s[4], prel[4];
  const int b = blockIdx.x, tid = threadIdx.x, lane = tid&63, wid = tid>>6;
  for (int i=tid;i<128;i+=256){
    Bv[i]=B1v[(long)b*128+i]; Vv[i]=Vn[(long)b*128+i]; qs[i]=qn[(long)b*256+i];
    gA[i]=lin_pg[i]; bA[i]=lin_pbeta[i];
    if (LAYER==1){ W0s[i]=W0row[(long)b*128+i]; g0[i]=ln_pg0[i]; b0[i]=ln_pbeta0[i]; }
  }
  __syncthreads();
  for (int idx=tid; idx<512; idx+=256){
    int h = idx>>7, cc = idx&127;
    float acc=0.f;
#pragma unroll
    for (int d=0; d<32; d++) acc += Wpred[cc*256 + h*32 + d]*qs[h*32+d];
    us[h][cc]=acc;
  }
  if (tid<4){
    float acc=0.f;
#pragma unroll
    for (int d=0;d<32;d++) acc += bpred[tid*32+d]*qs[tid*32+d];
    c0s[tid]=acc; prel[tid]=p_rel_l1[tid];
  }
  const float sb = sb1[b];
  float sp0=0.f, omsp=0.f;
  if (LAYER==1){ sp0 = 1.f/(1.f+expf(-skip_p[0])); omsp = 1.f - sp0; }
  __syncthreads();
  const float scale = 0.17677669529663687f;  // 1/sqrt(32)
  for (int p = wid; p < 106; p += 4){
    int c1 = lane, c2 = lane+64;
    float a1v = A1[p*128+c1], a2v = A1[p*128+c2];
    float u1 = Up[p*128+c1],  u2 = Up[p*128+c2];
    float bv1 = Bv[c1], bv2 = Bv[c2];
    float dot = wsum(a1v*bv1 + a2v*bv2);
    float var = (sa1[p] + 2.f*dot + sb) * (1.f/128.f);
    float inv = rsqrtf(var + 1e-5f);
    float x1 = (a1v+bv1)*inv*gA[c1] + bA[c1] + u1 + Vv[c1];
    float x2 = (a2v+bv2)*inv*gA[c2] + bA[c2] + u2 + Vv[c2];
    float r1, r2;
    if (LAYER==1){
      float t1 = sp0*W0s[c1] + omsp*x1 + u1 + Vv[c1];
      float t2 = sp0*W0s[c2] + omsp*x2 + u2 + Vv[c2];
      float m = wsum(t1+t2)*(1.f/128.f);
      float d1=t1-m, d2=t2-m;
      float v2s = wsum(d1*d1+d2*d2)*(1.f/128.f);
      float inv2 = rsqrtf(v2s+1e-5f);
      float y1 = d1*inv2*g0[c1]+b0[c1];
      float y2 = d2*inv2*g0[c2]+b0[c2];
      r1 = elu_f(y1); r2 = elu_f(y2);
    } else { r1 = x1; r2 = x2; }
    tile[p][c1]=r1; tile[p][c2]=r2;
    float s0 = r1*us[0][c1] + r2*us[0][c2];
    float s1 = r1*us[1][c1] + r2*us[1][c2];
    float s2 = r1*us[2][c1] + r2*us[2][c2];
    float s3 = r1*us[3][c1] + r2*us[3][c2];
    s0=wsum(s0); s1=wsum(s1); s2=wsum(s2); s3=wsum(s3);
    if (lane==0){
      ss[0][p]=(s0+c0s[0])*prel[0]*scale;
      ss[1][p]=(s1+c0s[1])*prel[1]*scale;
      ss[2][p]=(s2+c0s[2])*prel[2]*scale;
      ss[3][p]=(s3+c0s[3])*prel[3]*scale;
    }
  }
  __syncthreads();
  { // softmax: wave wid handles head wid over 106 entries
    int h = wid;
    int p1 = lane, p2 = lane+64;
    float v1 = (p1<106)? ss[h][p1] : -1e30f;
    float v2 = (p2<106)? ss[h][p2] : -1e30f;
    float mx = fmaxf(v1,v2);
#pragma unroll
    for (int o=32;o;o>>=1) mx = fmaxf(mx,__shfl_xor(mx,o));
    float e1 = (p1<106)? expf(v1-mx):0.f;
    float e2 = (p2<106)? expf(v2-mx):0.f;
    float den = wsum(e1+e2);
    float rinv = 1.f/den;
    if (p1<106) ss[h][p1]=e1*rinv;
    if (p2<106) ss[h][p2]=e2*rinv;
  }
  __syncthreads();
  for (int idx=tid; idx<512; idx+=256){
    int h = idx>>7, cc = idx&127;
    float acc=0.f;
    for (int p=0;p<106;p++) acc += ss[h][p]*tile[p][cc];
    ys[h][cc]=acc;
  }
  __syncthreads();
  if (tid<128){
    int h = tid>>5, d = tid&31;
    float acc = bpred[128 + tid];
    for (int cc=0;cc<128;cc++) acc += ys[h][cc]*Wpred[cc*256 + 128 + h*32 + d];
    agg_out[(long)b*128 + tid] = acc;
  }
}

__global__ void logits_kernel(const float* __restrict__ xn, const float* __restrict__ cls_w,
                              const float* __restrict__ cls_b, float* __restrict__ out)
{
  int row = blockIdx.x*4 + (threadIdx.x>>6);
  int lane = threadIdx.x&63;
  const float* x = xn + (long)row*128;
  float a0=0.f,a1=0.f;
#pragma unroll
  for (int i=0;i<2;i++){
    int c = lane + i*64;
    float xv = x[c];
    a0 += xv*cls_w[c*2];
    a1 += xv*cls_w[c*2+1];
  }
  a0 = wsum(a0); a1 = wsum(a1);
  if (lane==0){ out[row*2]=a0+cls_b[0]; out[row*2+1]=a1+cls_b[1]; }
}

__global__ void fill_att(float4* __restrict__ att4, long n4, float val){
  long i = (long)blockIdx.x*blockDim.x + threadIdx.x;
  long stride = (long)gridDim.x*blockDim.x;
  float4 v = make_float4(val,val,val,val);
  for (; i<n4; i+=stride) att4[i]=v;
}

__global__ void fix_att(float4* __restrict__ att4, float val){
  int i = blockIdx.x*256 + threadIdx.x;   // 2048*106 total
  if (i >= 2048*106) return;
  int b = i/106, j = i%106;
  att4[(long)b*11449 + 1 + j] = make_float4(val,val,val,val);
}

extern "C" void kernel_launch(void* const* d_in, const int* in_sizes, int n_in,
                              void* d_out, int out_size, void* d_ws, size_t ws_size,
                              hipStream_t stream) {
  const float* news_emb = (const float*)d_in[0];
  const float* base_embs= (const float*)d_in[1];
  const float* ctx_w  = (const float*)d_in[2];
  const float* ctx_b  = (const float*)d_in[3];
  const float* proj_w = (const float*)d_in[4];
  const float* proj_b = (const float*)d_in[5];
  const float* fus_w  = (const float*)d_in[6];
  const float* fus_b  = (const float*)d_in[7];
  const float* enc_w  = (const float*)d_in[8];
  const float* enc_b  = (const float*)d_in[9];
  const float* enc_g  = (const float*)d_in[10];
  const float* enc_beta=(const float*)d_in[11];
  const float* lin_nw = (const float*)d_in[12];
  const float* lin_nb = (const float*)d_in[13];
  const float* lin_ng = (const float*)d_in[14];
  const float* lin_nbeta=(const float*)d_in[15];
  const float* kqv_nw = (const float*)d_in[16];
  const float* kqv_nb = (const float*)d_in[17];
  const float* out_nw = (const float*)d_in[18];
  const float* out_nb = (const float*)d_in[19];
  const float* skip_n = (const float*)d_in[20];
  const float* ln_ng  = (const float*)d_in[21];
  const float* ln_nbeta=(const float*)d_in[22];
  const float* lin_pw = (const float*)d_in[23];
  const float* lin_pb = (const float*)d_in[24];
  const float* lin_pg = (const float*)d_in[25];
  const float* lin_pbeta=(const float*)d_in[26];
  const float* kqv_pw = (const float*)d_in[27];
  const float* kqv_pb = (const float*)d_in[28];
  const float* out_pw = (const float*)d_in[29];
  const float* out_pb = (const float*)d_in[30];
  const float* skip_p = (const float*)d_in[31];
  const float* ln_pg  = (const float*)d_in[32];
  const float* ln_pbeta=(const float*)d_in[33];
  const float* a_rel  = (const float*)d_in[34];
  const float* m_rel  = (const float*)d_in[35];
  const float* p_rel  = (const float*)d_in[36];
  const float* cls_w  = (const float*)d_in[37];
  const float* cls_b  = (const float*)d_in[38];
  (void)in_sizes; (void)n_in; (void)out_size; (void)d_ws; (void)ws_size;

  float* out = (float*)d_out;
  float* S = out + 4096;            // att region used as scratch; filled last
  float* news_ctx = S + 0;          // 2048*128
  float* pred_base= S + 262144;     // 106*128
  float* Ub   = S + 275712;         // 106*128
  float* Vb   = S + 289280;         // 2048*128
  float* A1   = S + 551424;         // 106*128  (U1 centered)
  float* sa1  = S + 564992;         // 128
  float* B1v  = S + 565120;         // 2048*128 (V1 centered)
  float* sb1  = S + 827264;         // 2048
  float* encpre=S + 829312;         // 2048*128
  float* xn_enc=S + 1091456;        // 2048*128
  float* linn = S + 1353600;        // 2048*128
  float* xn1  = S + 1615744;        // 2048*128
  float* Wnews= S + 1877888;        // 2*128*256
  float* bnews= S + 1943424;        // 2*256
  float* Wpred= S + 1943936;        // 2*128*256
  float* bpred= S + 2009472;        // 2*256
  float* qnv0 = S + 2009984;        // 2048*256
  float* aggb = S + 2534272;        // 2048*128
  float* onb  = S + 2796416;        // 2048*128
  float* W0row= S + 3058560;        // 2048*128
  float* xnA  = S + 3320704;        // 2048*128
  float* xnB  = S + 3582848;        // 2048*128

  dim3 blk(256);
  // Input projections (K=1024 GEMMs)
  gemm_bias<1024,128,false><<<256,blk,0,stream>>>(news_emb,1024,ctx_w,ctx_b,news_ctx,2048);
  gemm_bias<1024,128,false><<<14, blk,0,stream>>>(base_embs,1024,proj_w,proj_b,pred_base,106);
  gemm_bias<1024,128,false><<<256,blk,0,stream>>>(news_emb,1024,enc_w,enc_b,encpre,2048);
  ln_kernel<0><<<512,blk,0,stream>>>(encpre,nullptr,nullptr,enc_g,enc_beta,nullptr,xn_enc,2048);
  // fusion low-rank parts: xp0[b,p] = Ub[p] + Vb[b]
  gemm_bias<128,128,false><<<14, blk,0,stream>>>(pred_base,128,fus_w,fus_b,Ub,106);
  gemm_bias<128,128,false><<<256,blk,0,stream>>>(news_ctx,128,fus_w+128*128,nullptr,Vb,2048);
  // lin_p folded: U1 = Ub@lin_pw ; V1 = Vb@lin_pw + lin_pb ; center + norms
  gemm_bias<128,128,false><<<14, blk,0,stream>>>(Ub,128,lin_pw,nullptr,A1,106);
  gemm_bias<128,128,false><<<256,blk,0,stream>>>(Vb,128,lin_pw,lin_pb,B1v,2048);
  center_stats<<<27, blk,0,stream>>>(A1,sa1,106);
  center_stats<<<512,blk,0,stream>>>(B1v,sb1,2048);
  // news lin
  gemm_bias<128,128,false><<<256,blk,0,stream>>>(xn_enc,128,lin_nw,lin_nb,linn,2048);
  ln_kernel<1><<<512,blk,0,stream>>>(linn,nullptr,xn_enc,lin_ng,lin_nbeta,nullptr,xn1,2048);
  // fold rel matrices into kqv weights
  for (int l=0;l<2;l++){
    float* Wp = Wpred + l*32768; float* bp = bpred + l*256;
    float* Wn = Wnews + l*32768; float* bn = bnews + l*256;
    fold_rel<<<4,blk,0,stream>>>(kqv_pw + l*49152, kqv_pb + l*384, 0,   a_rel + (l*2+1)*4096, Wp, bp, 0);
    fold_rel<<<4,blk,0,stream>>>(kqv_pw + l*49152, kqv_pb + l*384, 256, m_rel + (l*2+1)*4096, Wp, bp, 128);
    fold_rel<<<4,blk,0,stream>>>(kqv_nw + l*49152, kqv_nb + l*384, 256, m_rel + (l*2+0)*4096, Wn, bn, 128);
    copy_q<<<64,blk,0,stream>>>(kqv_nw + l*49152, kqv_nb + l*384, Wn, bn);
  }
  // ---- layer 0 ----
  gemm_bias<128,256,false><<<256,blk,0,stream>>>(xn1,128,Wnews,bnews,qnv0,2048);
  attn_kernel<0><<<2048,blk,0,stream>>>(A1,Ub,sa1,B1v,Vb,sb1,qnv0,Wpred,bpred,p_rel+4,
      lin_pg,lin_pbeta,nullptr,nullptr,nullptr,nullptr,aggb);
  gemm_bias<128,128,true><<<256,blk,0,stream>>>(aggb,128,out_nw,out_nb,onb,2048);
  ln_kernel<2><<<512,blk,0,stream>>>(onb,xn1,xn_enc,ln_ng,ln_nbeta,skip_n,xnA,2048);
  // pred-side row update for layer-1 xp (uses layer-0 v0 = qnv0 cols 128..255)
  gemm_bias<128,128,true><<<256,blk,0,stream>>>(qnv0+128,256,out_pw,out_pb,W0row,2048);
  // ---- layer 1 ----
  gemm_bias<128,256,false><<<256,blk,0,stream>>>(xnA,128,Wnews+32768,bnews+256,qnv0,2048);
  attn_kernel<1><<<2048,blk,0,stream>>>(A1,Ub,sa1,B1v,Vb,sb1,qnv0,Wpred+32768,bpred+256,p_rel+12,
      lin_pg,lin_pbeta,W0row,ln_pg,ln_pbeta,skip_p,aggb);
  gemm_bias<128,128,true><<<256,blk,0,stream>>>(aggb,128,out_nw+16384,out_nb+128,onb,2048);
  ln_kernel<2><<<512,blk,0,stream>>>(onb,xnA,xnA,ln_ng+128,ln_nbeta+128,skip_n+1,xnB,2048);
  // outputs
  logits_kernel<<<512,blk,0,stream>>>(xnB,cls_w,cls_b,out);
  fill_att<<<4096,blk,0,stream>>>(reinterpret_cast<float4*>(S), 23447552L, 1.f/107.f);
  fix_att<<<848,blk,0,stream>>>(reinterpret_cast<float4*>(S), 1.f/217088.f);
}